// Round 21
// baseline (1126.953 us; speedup 1.0000x reference)
//
#include <hip/hip_runtime.h>
#include <hip/hip_bf16.h>

#define N_NODES 100000
#define N_EDGES 1600000
#define SCAN_BLOCKS ((N_NODES+255)/256)   // 391
#define NWAVE (N_NODES/16)                // 6250 node-batches / waves

using bf16 = __hip_bfloat16;
typedef unsigned int u32;
typedef __attribute__((ext_vector_type(8))) short short8;
typedef __attribute__((ext_vector_type(4))) float f32x4;

static __device__ __forceinline__ float b2f(bf16 v){ return __bfloat162float(v); }

static __device__ __forceinline__ float ldf(const void* p, long i, int f32m){
  return f32m ? ((const float*)p)[i] : b2f(((const bf16*)p)[i]);
}

static __device__ __forceinline__ u32 f2bf_rne(float f){
  u32 b = __float_as_uint(f);
  return (b + 0x7fffu + ((b>>16)&1u)) >> 16;
}

// ---------------- dtype detection (device-side, deterministic) ----------------
__global__ void k_detect(const u32* __restrict__ xw, const int* __restrict__ eiw,
                         int* __restrict__ flags){
  __shared__ int s_wild, s_nzodd;
  if(threadIdx.x==0){ s_wild=0; s_nzodd=0; }
  __syncthreads();
  int wild=0, nz=0;
  for(int k=threadIdx.x;k<2048;k+=256){
    u32 w  = xw[k];
    u32 lo = w & 0xffffu;
    int e  = (int)((lo>>7)&0xffu);
    if((lo & 0x7fffu)!=0u && (e<90 || e>160)) wild++;
    if(eiw[2*k+1]!=0) nz++;
  }
  atomicAdd(&s_wild, wild);
  atomicAdd(&s_nzodd, nz);
  __syncthreads();
  if(threadIdx.x==0){
    flags[0] = (s_wild > 512) ? 1 : 0;   // 1: floats are f32
    flags[1] = (s_nzodd == 0) ? 1 : 0;   // 1: indices are int64
  }
}

__global__ void k_zero2(int* __restrict__ a, int* __restrict__ b,
                        int* __restrict__ hist){
  int i = blockIdx.x*256 + threadIdx.x;
  if(i<N_NODES){ a[i]=0; b[i]=0; }
  if(blockIdx.x==0 && threadIdx.x<256) hist[threadIdx.x]=0;
}

// convert emb weights to f32 workspace
__global__ void k_cvt(const void* __restrict__ W, const void* __restrict__ b,
                      const int* __restrict__ flags, float* __restrict__ Wo,
                      float* __restrict__ bo_){
  int i = blockIdx.x*256 + threadIdx.x;
  int f32m = flags[0];
  if(i<8000) Wo[i] = ldf(W,i,f32m);
  if(i<80)   bo_[i] = ldf(b,i,f32m);
}

// ---------------- CSR build ----------------

__global__ void k_count(const int* __restrict__ ei, const int* __restrict__ flags,
                        int* __restrict__ deg){
  int e = blockIdx.x*256 + threadIdx.x;
  int i64 = flags[1];
  if(e < N_EDGES){
    long di = i64 ? 2l*(N_EDGES + e) : (long)(N_EDGES + e);
    atomicAdd(&deg[ei[di]], 1);
  }
}

__global__ void k_scan1(const int* __restrict__ deg, int* __restrict__ off,
                        int* __restrict__ bsum){
  const int t = threadIdx.x, lane = t&63, wid = t>>6;
  const int i = blockIdx.x*256 + t;
  int v = (i<N_NODES) ? deg[i] : 0;
  const int orig = v;
  #pragma unroll
  for(int d=1; d<64; d<<=1){ int u = __shfl_up(v,d); if(lane>=d) v += u; }
  __shared__ int wsum[4];
  if(lane==63) wsum[wid] = v;
  __syncthreads();
  int wbase = 0;
  for(int k=0;k<wid;k++) wbase += wsum[k];
  if(i<N_NODES) off[i] = wbase + v - orig;
  if(t==255) bsum[blockIdx.x] = wbase + v;
}

__global__ void k_scan2(const int* __restrict__ bsum, int* __restrict__ bbase){
  const int t = threadIdx.x, lane = t&63, wid = t>>6;
  int v = (t<SCAN_BLOCKS) ? bsum[t] : 0;
  const int orig = v;
  #pragma unroll
  for(int d=1; d<64; d<<=1){ int u = __shfl_up(v,d); if(lane>=d) v += u; }
  __shared__ int wsum[8];
  if(lane==63) wsum[wid] = v;
  __syncthreads();
  int wbase = 0;
  for(int k=0;k<wid;k++) wbase += wsum[k];
  if(t<SCAN_BLOCKS) bbase[t] = wbase + v - orig;
}

__global__ void k_scan3(int* __restrict__ off, const int* __restrict__ bbase){
  const int i = blockIdx.x*256 + threadIdx.x;
  if(i<N_NODES) off[i] += bbase[blockIdx.x];
  if(i==0) off[N_NODES] = N_EDGES;
}

// XCD-partitioned CSR fill
__global__ void k_fill(const int* __restrict__ ei, const void* __restrict__ ew,
                       const int* __restrict__ flags, const int* __restrict__ off,
                       int* __restrict__ cur, uint2* __restrict__ csr){
  const int xcd = blockIdx.x & 7;
  const int e = (blockIdx.x>>3)*256 + threadIdx.x;
  const int i64 = flags[1], f32m = flags[0];
  if(e < N_EDGES){
    int d = ei[i64 ? 2l*(N_EDGES+e) : (long)(N_EDGES+e)];
    if(d/12500 == xcd){
      int s = ei[i64 ? 2l*e : (long)e];
      int p = atomicAdd(&cur[d], 1);
      csr[off[d]+p] = make_uint2((u32)s, __float_as_uint(ldf(ew, e, f32m)));
    }
  }
}

// ---------------- degree-stratified permutation (load balancing) ----------------
// hist over clamped degree -> exclusive prefix -> cursor scatter.
// Wave w then processes nodes perm[w + k*NWAVE], k=0..15: one node per
// degree stratum -> per-wave work ~= mean -> flat retirement, no tail.

__global__ void k_hist(const int* __restrict__ deg, int* __restrict__ hist){
  int i = blockIdx.x*256 + threadIdx.x;
  if(i<N_NODES) atomicAdd(&hist[min(deg[i],255)], 1);
}

__global__ void k_hscan(const int* __restrict__ hist, int* __restrict__ hcur){
  const int t = threadIdx.x, lane = t&63, wid = t>>6;   // 256 threads
  int v = hist[t];
  const int orig = v;
  #pragma unroll
  for(int d=1; d<64; d<<=1){ int u = __shfl_up(v,d); if(lane>=d) v += u; }
  __shared__ int wsum[4];
  if(lane==63) wsum[wid] = v;
  __syncthreads();
  int wbase = 0;
  for(int k=0;k<wid;k++) wbase += wsum[k];
  hcur[t] = wbase + v - orig;          // exclusive prefix = scatter cursor
}

__global__ void k_scatter(const int* __restrict__ deg, int* __restrict__ hcur,
                          int* __restrict__ perm){
  int i = blockIdx.x*256 + threadIdx.x;
  if(i<N_NODES){
    int pos = atomicAdd(&hcur[min(deg[i],255)], 1);
    perm[pos] = i;
  }
}

// ---------------- B-fragment pre-pack for MFMA ----------------

__global__ void k_packb(const void* __restrict__ Wl, const void* __restrict__ Wr,
                        const int* __restrict__ flags, int CIN, int COUT,
                        int KT, int NT, short* __restrict__ out){
  int idx = blockIdx.x*256 + threadIdx.x;
  int total = KT*NT*512;
  if(idx < total){
    int jj = idx & 7;
    int l  = (idx>>3) & 63;
    int tile = idx >> 9;
    int nt = tile % NT, kt = tile / NT;
    int k   = kt*32 + ((l>>4)<<3) + jj;
    int col = nt*16 + (l&15);
    int khalf = (KT/2)*32;
    float v = 0.f;
    if(col < COUT){
      int f32m = flags[0];
      if(k < khalf){ if(k < CIN) v = ldf(Wl,(long)k*COUT+col,f32m); }
      else { int ch = k - khalf; if(ch < CIN) v = ldf(Wr,(long)ch*COUT+col,f32m); }
    }
    out[idx] = (short)f2bf_rne(v);
  }
}

// ---------------- embedding: LDS x-tile + global W (L1), bf16 output ----------------

__global__ __launch_bounds__(256) void k_embed(const void* __restrict__ x,
                                               const float* __restrict__ W,
                                               const float* __restrict__ b,
                                               const int* __restrict__ flags,
                                               bf16* __restrict__ h){
  __shared__ float xs[100][65];
  const int t = threadIdx.x;
  const int n0 = blockIdx.x*64;
  if(flags[0]){
    const float* xf = (const float*)x;
    for(int idx=t; idx<1600; idx+=256){
      int n = idx/25, q = idx-25*(idx/25);
      float4 v = (n0+n < N_NODES) ? *(const float4*)(xf + (long)(n0+n)*100 + 4*q)
                                  : make_float4(0.f,0.f,0.f,0.f);
      xs[4*q+0][n]=v.x; xs[4*q+1][n]=v.y; xs[4*q+2][n]=v.z; xs[4*q+3][n]=v.w;
    }
  } else {
    const u32* xu = (const u32*)x;
    for(int idx=t; idx<3200; idx+=256){
      int n = idx/50, q = idx-50*(idx/50);
      u32 v = (n0+n < N_NODES) ? xu[(long)(n0+n)*50 + q] : 0u;
      xs[2*q+0][n]=__uint_as_float(v<<16);
      xs[2*q+1][n]=__uint_as_float(v&0xffff0000u);
    }
  }
  __syncthreads();

  const int ng = t&15, og = t>>4;
  float acc[4][5];
  #pragma unroll
  for(int j=0;j<5;j++){
    float bj = b[og*5+j];
    #pragma unroll
    for(int i=0;i<4;i++) acc[i][j] = bj;
  }
  #pragma unroll 2
  for(int c=0;c<100;c++){
    float xv[4];
    #pragma unroll
    for(int i=0;i<4;i++) xv[i] = xs[c][ng*4+i];
    #pragma unroll
    for(int j=0;j<5;j++){
      float wj = W[c*80+og*5+j];
      #pragma unroll
      for(int i=0;i<4;i++) acc[i][j] = fmaf(xv[i], wj, acc[i][j]);
    }
  }
  #pragma unroll
  for(int i=0;i<4;i++){
    int n = n0 + ng*4 + i;
    if(n < N_NODES){
      #pragma unroll
      for(int j=0;j<5;j++)
        h[(long)n*80 + og*5+j] = __float2bfloat16(fmaxf(acc[i][j], 0.f));
    }
  }
}

// ---------------- fused SAGE layer: bf16-row gather + MFMA matvec ----------------
// Round-17 body (validated 525us) + degree-stratified perm indirection.
// block = 2 waves; wave widx processes nodes perm[widx + k*NWAVE], k=0..15.

template<int CIN, int COUT, bool LAST>
__global__ __launch_bounds__(128,6) void k_sage(
    const void* __restrict__ hin, const int* __restrict__ off,
    const uint2* __restrict__ csr, const int* __restrict__ perm,
    const short* __restrict__ Wb, const void* __restrict__ bias,
    const int* __restrict__ flags, bf16* __restrict__ hout, void* __restrict__ outp)
{
  constexpr int RB   = CIN*2;                // bf16 row bytes: 128 or 160
  constexpr int KHT  = (CIN+31)/32;          // K-tiles per half: 2 or 3
  constexpr int KT   = 2*KHT;                // 4 or 6
  constexpr int NT   = (COUT+15)/16;         // 4 or 2
  constexpr int ROWB = KT*32*2;              // 256 or 384 bytes per A-row
  constexpr int LPE  = CIN/8;                // lanes per edge-row: 8 or 10
  constexpr int EPW  = 64/LPE;               // edges per wave load: 8 or 6

  __shared__ char smem[2*16*ROWB];

  const int f32m = flags[0];
  const int lane = threadIdx.x&63, wid = threadIdx.x>>6;
  const int widx = blockIdx.x*2 + wid;       // wave index 0..NWAVE-1
  char* lds = smem + wid*16*ROWB;

  const int sub = lane/LPE;
  const int cl  = lane - sub*LPE;
  const bool lact = (sub < EPW);
  const char* hinb = (const char*)hin;

  // ---- phase 1: gather + A-row staging ----
  for(int tt=0; tt<16; ++tt){
    const int node = perm[widx + tt*NWAVE];

    float a[8];
    #pragma unroll
    for(int k=0;k<8;k++) a[k]=0.f;

    const int e0 = off[node], e1 = off[node+1];

    #define ACC8(rr,ww) \
      a[0]=fmaf(ww,__uint_as_float(rr.x<<16),a[0]); \
      a[1]=fmaf(ww,__uint_as_float(rr.x&0xffff0000u),a[1]); \
      a[2]=fmaf(ww,__uint_as_float(rr.y<<16),a[2]); \
      a[3]=fmaf(ww,__uint_as_float(rr.y&0xffff0000u),a[3]); \
      a[4]=fmaf(ww,__uint_as_float(rr.z<<16),a[4]); \
      a[5]=fmaf(ww,__uint_as_float(rr.z&0xffff0000u),a[5]); \
      a[6]=fmaf(ww,__uint_as_float(rr.w<<16),a[6]); \
      a[7]=fmaf(ww,__uint_as_float(rr.w&0xffff0000u),a[7]);

    for(int base=e0; base<e1; base+=64){
      const int cnt = min(64, e1-base);
      uint2 ev = (lane<cnt) ? csr[base+lane] : make_uint2(0u,0u);
      int   sv = (int)ev.x;
      float wv = LAST ? 1.f : __uint_as_float(ev.y);
      for(int j=0; j<cnt; j+=4*EPW){
        int ei0 = j+sub, ei1 = j+EPW+sub, ei2 = j+2*EPW+sub, ei3 = j+3*EPW+sub;
        bool v0 = lact && (ei0<cnt), v1 = lact && (ei1<cnt);
        bool v2 = lact && (ei2<cnt), v3 = lact && (ei3<cnt);
        int x0 = v0?ei0:0, x1 = v1?ei1:0, x2 = v2?ei2:0, x3 = v3?ei3:0;
        int   s0=__shfl(sv,x0), s1=__shfl(sv,x1), s2=__shfl(sv,x2), s3=__shfl(sv,x3);
        float w0=__shfl(wv,x0)*(v0?1.f:0.f), w1=__shfl(wv,x1)*(v1?1.f:0.f);
        float w2=__shfl(wv,x2)*(v2?1.f:0.f), w3=__shfl(wv,x3)*(v3?1.f:0.f);
        uint4 r0 = *(const uint4*)(hinb + (long)s0*RB + 16*cl);
        uint4 r1 = *(const uint4*)(hinb + (long)s1*RB + 16*cl);
        uint4 r2 = *(const uint4*)(hinb + (long)s2*RB + 16*cl);
        uint4 r3 = *(const uint4*)(hinb + (long)s3*RB + 16*cl);
        ACC8(r0,w0); ACC8(r1,w1); ACC8(r2,w2); ACC8(r3,w3);
      }
    }
    #undef ACC8

    // reduce across edge groups -> lane q<LPE holds channels 8q..8q+7
    if(LPE==8){
      #pragma unroll
      for(int k=0;k<8;k++){
        a[k]+=__shfl_xor(a[k],8); a[k]+=__shfl_xor(a[k],16); a[k]+=__shfl_xor(a[k],32);
      }
    } else {
      #pragma unroll
      for(int k=0;k<8;k++){
        a[k] = __shfl(a[k],cl)    + __shfl(a[k],cl+10) + __shfl(a[k],cl+20)
             + __shfl(a[k],cl+30) + __shfl(a[k],cl+40) + __shfl(a[k],cl+50);
      }
    }
    const float inv = 1.f/fmaxf((float)(e1-e0), 1.f);

    const int sx = (tt&7)<<4;                       // row XOR swizzle
    if(lane < LPE){                                 // agg: 16B per lane
      u32 p0 = f2bf_rne(a[0]*inv) | (f2bf_rne(a[1]*inv)<<16);
      u32 p1 = f2bf_rne(a[2]*inv) | (f2bf_rne(a[3]*inv)<<16);
      u32 p2 = f2bf_rne(a[4]*inv) | (f2bf_rne(a[5]*inv)<<16);
      u32 p3 = f2bf_rne(a[6]*inv) | (f2bf_rne(a[7]*inv)<<16);
      int ob = tt*ROWB + lane*16;
      *(uint4*)(lds + (ob^sx)) = make_uint4(p0,p1,p2,p3);
    }
    if(CIN==80 && lane>=10 && lane<12){             // agg K-pad bytes 160..191
      int ob = tt*ROWB + lane*16;
      *(uint4*)(lds + (ob^sx)) = make_uint4(0u,0u,0u,0u);
    }
    const char* hsb = hinb + (long)__builtin_amdgcn_readfirstlane(node)*RB;
    if(lane < RB/16){                               // raw self-row copy
      uint4 hv = *(const uint4*)(hsb + lane*16);
      int ob = tt*ROWB + KHT*64 + lane*16;
      *(uint4*)(lds + (ob^sx)) = hv;
    }
    if(CIN==80 && lane>=20 && lane<22){             // h K-pad bytes 352..383
      int ob = tt*ROWB + KHT*64 + (lane-10)*16;
      *(uint4*)(lds + (ob^sx)) = make_uint4(0u,0u,0u,0u);
    }
  }

  // ---- phase 2: MFMA matvec (wave-local LDS reads) ----
  f32x4 acc[NT];
  #pragma unroll
  for(int nt=0; nt<NT; ++nt){
    int col = nt*16 + (lane&15);
    float bv = (col<COUT) ? ldf(bias,col,f32m) : 0.f;
    acc[nt] = (f32x4){bv,bv,bv,bv};
  }
  const int arow = lane&15, kgrp = lane>>4;
  #pragma unroll
  for(int kt=0; kt<KT; ++kt){
    int ob = arow*ROWB + kt*64 + kgrp*16;
    short8 a8 = *(const short8*)(lds + (ob ^ ((arow&7)<<4)));
    #pragma unroll
    for(int nt=0; nt<NT; ++nt){
      short8 b8 = *(const short8*)(Wb + ((long)(kt*NT+nt)*64 + lane)*8);
      acc[nt] = __builtin_amdgcn_mfma_f32_16x16x32_bf16(a8, b8, acc[nt], 0,0,0);
    }
  }

  // ---- epilogue: L2-norm per row, relu, store ----
  float sq[4];
  #pragma unroll
  for(int r=0;r<4;r++){
    float s = 0.f;
    #pragma unroll
    for(int nt=0;nt<NT;nt++){ float v = acc[nt][r]; s = fmaf(v,v,s); }
    #pragma unroll
    for(int d=1; d<16; d<<=1) s += __shfl_xor(s, d);
    sq[r] = s;
  }
  #pragma unroll
  for(int r=0;r<4;r++){
    float rn = 1.f/fmaxf(sqrtf(sq[r]), 1e-12f);
    const int slot = 4*(lane>>4) + r;
    const int node = perm[widx + slot*NWAVE];
    #pragma unroll
    for(int nt=0;nt<NT;nt++){
      int col = nt*16 + (lane&15);
      float v = acc[nt][r]*rn;
      if(!LAST) v = fmaxf(v,0.f);
      if(col < COUT){
        if(LAST){
          long oi = (long)node*COUT + col;
          if(f32m) ((float*)outp)[oi] = v;
          else     ((bf16*)outp)[oi]  = __float2bfloat16(v);
        } else {
          hout[(long)node*64 + col] = __float2bfloat16(v);
        }
      }
    }
  }
}

// ---------------- launch ----------------

extern "C" void kernel_launch(void* const* d_in, const int* in_sizes, int n_in,
                              void* d_out, int out_size, void* d_ws, size_t ws_size,
                              hipStream_t stream){
  const void* x    = d_in[0];
  const int*  ei   = (const int*)d_in[1];
  const void* ew   = d_in[2];
  const void* embW = d_in[3];
  const void* embB = d_in[4];
  const void *Wl0=d_in[5],  *Wr0=d_in[6],  *b0=d_in[7];
  const void *Wl1=d_in[8],  *Wr1=d_in[9],  *b1=d_in[10];
  const void *Wl2=d_in[11], *Wr2=d_in[12], *b2=d_in[13];
  const void *Wl3=d_in[14], *Wr3=d_in[15], *b3=d_in[16];
  const void *Wlo=d_in[17], *Wro=d_in[18], *bo=d_in[19];

  // 256B-aligned workspace carves
  char* w = (char*)d_ws;
  auto carve = [&](size_t nbytes)->char*{
    char* r = w; w += (nbytes + 255) & ~(size_t)255; return r;
  };
  int*   flags   = (int*)carve(16);
  int*   deg     = (int*)carve((size_t)N_NODES*4);
  int*   cur     = (int*)carve((size_t)N_NODES*4);
  int*   off     = (int*)carve((size_t)(N_NODES+1)*4);
  int*   bsum    = (int*)carve((size_t)SCAN_BLOCKS*4);
  int*   bbase   = (int*)carve((size_t)SCAN_BLOCKS*4);
  int*   hist    = (int*)carve((size_t)256*4);
  int*   hcur    = (int*)carve((size_t)256*4);
  int*   perm    = (int*)carve((size_t)N_NODES*4);
  uint2* csr     = (uint2*)carve((size_t)N_EDGES*8);
  short* Wb0     = (short*)carve((size_t)6*4*512*2);
  short* Wb1     = (short*)carve((size_t)4*4*512*2);
  short* Wb2     = (short*)carve((size_t)4*4*512*2);
  short* Wb3     = (short*)carve((size_t)4*4*512*2);
  short* Wbo     = (short*)carve((size_t)4*2*512*2);
  float* Wef     = (float*)carve((size_t)8000*4);
  float* bef     = (float*)carve((size_t)80*4);
  bf16*  hE      = (bf16*)carve((size_t)N_NODES*80*2);   // embed out, 160B rows
  bf16*  hA      = (bf16*)carve((size_t)N_NODES*64*2);   // 128B rows
  bf16*  hB      = (bf16*)carve((size_t)N_NODES*64*2);

  k_detect<<<1, 256, 0, stream>>>((const u32*)x, ei, flags);
  k_zero2<<<(N_NODES+255)/256, 256, 0, stream>>>(deg, cur, hist);
  k_count<<<N_EDGES/256, 256, 0, stream>>>(ei, flags, deg);
  k_scan1<<<SCAN_BLOCKS, 256, 0, stream>>>(deg, off, bsum);
  k_scan2<<<1, 512, 0, stream>>>(bsum, bbase);
  k_scan3<<<SCAN_BLOCKS, 256, 0, stream>>>(off, bbase);
  k_fill <<<8*(N_EDGES/256), 256, 0, stream>>>(ei, ew, flags, off, cur, csr);

  k_hist   <<<SCAN_BLOCKS, 256, 0, stream>>>(deg, hist);
  k_hscan  <<<1, 256, 0, stream>>>(hist, hcur);
  k_scatter<<<SCAN_BLOCKS, 256, 0, stream>>>(deg, hcur, perm);

  k_cvt  <<<32, 256, 0, stream>>>(embW, embB, flags, Wef, bef);
  k_packb<<<48, 256, 0, stream>>>(Wl0, Wr0, flags, 80, 64, 6, 4, Wb0);
  k_packb<<<32, 256, 0, stream>>>(Wl1, Wr1, flags, 64, 64, 4, 4, Wb1);
  k_packb<<<32, 256, 0, stream>>>(Wl2, Wr2, flags, 64, 64, 4, 4, Wb2);
  k_packb<<<32, 256, 0, stream>>>(Wl3, Wr3, flags, 64, 64, 4, 4, Wb3);
  k_packb<<<16, 256, 0, stream>>>(Wlo, Wro, flags, 64, 18, 4, 2, Wbo);

  k_embed<<<(N_NODES+63)/64, 256, 0, stream>>>(x, Wef, bef, flags, hE);

  const int NBLK = NWAVE/2;   // 3125 exact
  k_sage<80,64,false><<<NBLK, 128, 0, stream>>>(hE, off, csr, perm, Wb0, b0, flags, hA, nullptr);
  k_sage<64,64,false><<<NBLK, 128, 0, stream>>>(hA, off, csr, perm, Wb1, b1, flags, hB, nullptr);
  k_sage<64,64,false><<<NBLK, 128, 0, stream>>>(hB, off, csr, perm, Wb2, b2, flags, hA, nullptr);
  k_sage<64,64,false><<<NBLK, 128, 0, stream>>>(hA, off, csr, perm, Wb3, b3, flags, hB, nullptr);
  k_sage<64,18,true ><<<NBLK, 128, 0, stream>>>(hB, off, csr, perm, Wbo, bo, flags, nullptr, d_out);
}

// Round 22
// 523.915 us; speedup vs baseline: 2.1510x; 2.1510x over previous
//
#include <hip/hip_runtime.h>
#include <hip/hip_bf16.h>

#define N_NODES 100000
#define N_EDGES 1600000
#define SCAN_BLOCKS ((N_NODES+255)/256)   // 391

using bf16 = __hip_bfloat16;
typedef unsigned int u32;
typedef __attribute__((ext_vector_type(8))) short short8;
typedef __attribute__((ext_vector_type(4))) float f32x4;

static __device__ __forceinline__ float b2f(bf16 v){ return __bfloat162float(v); }

static __device__ __forceinline__ float ldf(const void* p, long i, int f32m){
  return f32m ? ((const float*)p)[i] : b2f(((const bf16*)p)[i]);
}

static __device__ __forceinline__ u32 f2bf_rne(float f){
  u32 b = __float_as_uint(f);
  return (b + 0x7fffu + ((b>>16)&1u)) >> 16;
}

// ---------------- dtype detection (device-side, deterministic) ----------------
__global__ void k_detect(const u32* __restrict__ xw, const int* __restrict__ eiw,
                         int* __restrict__ flags){
  __shared__ int s_wild, s_nzodd;
  if(threadIdx.x==0){ s_wild=0; s_nzodd=0; }
  __syncthreads();
  int wild=0, nz=0;
  for(int k=threadIdx.x;k<2048;k+=256){
    u32 w  = xw[k];
    u32 lo = w & 0xffffu;
    int e  = (int)((lo>>7)&0xffu);
    if((lo & 0x7fffu)!=0u && (e<90 || e>160)) wild++;
    if(eiw[2*k+1]!=0) nz++;
  }
  atomicAdd(&s_wild, wild);
  atomicAdd(&s_nzodd, nz);
  __syncthreads();
  if(threadIdx.x==0){
    flags[0] = (s_wild > 512) ? 1 : 0;   // 1: floats are f32
    flags[1] = (s_nzodd == 0) ? 1 : 0;   // 1: indices are int64
  }
}

__global__ void k_zero2(int* __restrict__ a, int* __restrict__ b){
  int i = blockIdx.x*256 + threadIdx.x;
  if(i<N_NODES){ a[i]=0; b[i]=0; }
}

// convert emb weights to f32 workspace (removes per-load dtype branch)
__global__ void k_cvt(const void* __restrict__ W, const void* __restrict__ b,
                      const int* __restrict__ flags, float* __restrict__ Wo,
                      float* __restrict__ bo_){
  int i = blockIdx.x*256 + threadIdx.x;
  int f32m = flags[0];
  if(i<8000) Wo[i] = ldf(W,i,f32m);
  if(i<80)   bo_[i] = ldf(b,i,f32m);
}

// ---------------- CSR build ----------------

__global__ void k_count(const int* __restrict__ ei, const int* __restrict__ flags,
                        int* __restrict__ deg){
  int e = blockIdx.x*256 + threadIdx.x;
  int i64 = flags[1];
  if(e < N_EDGES){
    long di = i64 ? 2l*(N_EDGES + e) : (long)(N_EDGES + e);
    atomicAdd(&deg[ei[di]], 1);
  }
}

// hierarchical exclusive scan of deg[0..N) -> off, block totals -> bsum
__global__ void k_scan1(const int* __restrict__ deg, int* __restrict__ off,
                        int* __restrict__ bsum){
  const int t = threadIdx.x, lane = t&63, wid = t>>6;
  const int i = blockIdx.x*256 + t;
  int v = (i<N_NODES) ? deg[i] : 0;
  const int orig = v;
  #pragma unroll
  for(int d=1; d<64; d<<=1){ int u = __shfl_up(v,d); if(lane>=d) v += u; }
  __shared__ int wsum[4];
  if(lane==63) wsum[wid] = v;
  __syncthreads();
  int wbase = 0;
  for(int k=0;k<wid;k++) wbase += wsum[k];
  if(i<N_NODES) off[i] = wbase + v - orig;          // block-local exclusive
  if(t==255) bsum[blockIdx.x] = wbase + v;          // block total
}

__global__ void k_scan2(const int* __restrict__ bsum, int* __restrict__ bbase){
  const int t = threadIdx.x, lane = t&63, wid = t>>6; // 512 threads, 8 waves
  int v = (t<SCAN_BLOCKS) ? bsum[t] : 0;
  const int orig = v;
  #pragma unroll
  for(int d=1; d<64; d<<=1){ int u = __shfl_up(v,d); if(lane>=d) v += u; }
  __shared__ int wsum[8];
  if(lane==63) wsum[wid] = v;
  __syncthreads();
  int wbase = 0;
  for(int k=0;k<wid;k++) wbase += wsum[k];
  if(t<SCAN_BLOCKS) bbase[t] = wbase + v - orig;    // exclusive block base
}

__global__ void k_scan3(int* __restrict__ off, const int* __restrict__ bbase){
  const int i = blockIdx.x*256 + threadIdx.x;
  if(i<N_NODES) off[i] += bbase[blockIdx.x];
  if(i==0) off[N_NODES] = N_EDGES;
}

// XCD-partitioned CSR fill (round-15 win): block b writes only its dst range.
__global__ void k_fill(const int* __restrict__ ei, const void* __restrict__ ew,
                       const int* __restrict__ flags, const int* __restrict__ off,
                       int* __restrict__ cur, uint2* __restrict__ csr){
  const int xcd = blockIdx.x & 7;
  const int e = (blockIdx.x>>3)*256 + threadIdx.x;
  const int i64 = flags[1], f32m = flags[0];
  if(e < N_EDGES){
    int d = ei[i64 ? 2l*(N_EDGES+e) : (long)(N_EDGES+e)];
    if(d/12500 == xcd){
      int s = ei[i64 ? 2l*e : (long)e];
      int p = atomicAdd(&cur[d], 1);
      csr[off[d]+p] = make_uint2((u32)s, __float_as_uint(ldf(ew, e, f32m)));
    }
  }
}

// ---------------- B-fragment pre-pack for MFMA ----------------

__global__ void k_packb(const void* __restrict__ Wl, const void* __restrict__ Wr,
                        const int* __restrict__ flags, int CIN, int COUT,
                        int KT, int NT, short* __restrict__ out){
  int idx = blockIdx.x*256 + threadIdx.x;
  int total = KT*NT*512;
  if(idx < total){
    int jj = idx & 7;
    int l  = (idx>>3) & 63;
    int tile = idx >> 9;             // kt*NT + nt
    int nt = tile % NT, kt = tile / NT;
    int k   = kt*32 + ((l>>4)<<3) + jj;
    int col = nt*16 + (l&15);
    int khalf = (KT/2)*32;
    float v = 0.f;
    if(col < COUT){
      int f32m = flags[0];
      if(k < khalf){ if(k < CIN) v = ldf(Wl,(long)k*COUT+col,f32m); }
      else { int ch = k - khalf; if(ch < CIN) v = ldf(Wr,(long)ch*COUT+col,f32m); }
    }
    out[idx] = (short)f2bf_rne(v);
  }
}

// ---------------- embedding: LDS x-tile + global W (L1), bf16 output ----------------

__global__ __launch_bounds__(256) void k_embed(const void* __restrict__ x,
                                               const float* __restrict__ W,
                                               const float* __restrict__ b,
                                               const int* __restrict__ flags,
                                               bf16* __restrict__ h){
  __shared__ float xs[100][65];     // [channel][node], pad 65
  const int t = threadIdx.x;
  const int n0 = blockIdx.x*64;
  if(flags[0]){                     // f32 x: float4 staging
    const float* xf = (const float*)x;
    for(int idx=t; idx<1600; idx+=256){
      int n = idx/25, q = idx-25*(idx/25);
      float4 v = (n0+n < N_NODES) ? *(const float4*)(xf + (long)(n0+n)*100 + 4*q)
                                  : make_float4(0.f,0.f,0.f,0.f);
      xs[4*q+0][n]=v.x; xs[4*q+1][n]=v.y; xs[4*q+2][n]=v.z; xs[4*q+3][n]=v.w;
    }
  } else {                          // bf16 x: uint staging (2 ch per u32)
    const u32* xu = (const u32*)x;
    for(int idx=t; idx<3200; idx+=256){
      int n = idx/50, q = idx-50*(idx/50);
      u32 v = (n0+n < N_NODES) ? xu[(long)(n0+n)*50 + q] : 0u;
      xs[2*q+0][n]=__uint_as_float(v<<16);
      xs[2*q+1][n]=__uint_as_float(v&0xffff0000u);
    }
  }
  __syncthreads();

  const int ng = t&15, og = t>>4;    // nodes ng*4..+3, outs og*5..+4
  float acc[4][5];
  #pragma unroll
  for(int j=0;j<5;j++){
    float bj = b[og*5+j];
    #pragma unroll
    for(int i=0;i<4;i++) acc[i][j] = bj;
  }
  #pragma unroll 2
  for(int c=0;c<100;c++){
    float xv[4];
    #pragma unroll
    for(int i=0;i<4;i++) xv[i] = xs[c][ng*4+i];
    #pragma unroll
    for(int j=0;j<5;j++){
      float wj = W[c*80+og*5+j];
      #pragma unroll
      for(int i=0;i<4;i++) acc[i][j] = fmaf(xv[i], wj, acc[i][j]);
    }
  }
  #pragma unroll
  for(int i=0;i<4;i++){
    int n = n0 + ng*4 + i;
    if(n < N_NODES){
      #pragma unroll
      for(int j=0;j<5;j++)
        h[(long)n*80 + og*5+j] = __float2bfloat16(fmaxf(acc[i][j], 0.f));
    }
  }
}

// ---------------- fused SAGE layer: bf16-row gather + MFMA matvec ----------------
// h rows are bf16, RB=CIN*2 bytes. Gather: LPE=CIN/8 lanes per edge read uint4
// (8 ch each); EPW=64/LPE edges per wave-load, 4-deep ILP. Unpack-fma into
// f32 a[8]. Reduce across edge groups (xor for LPE=8; 6-term bpermute for
// LPE=10). A-row staging: one uint4 LDS write/lane (agg, bf16-packed) + raw
// uint4 copy of self row. MFMA C=A·Wb; bias init; 16-group L2-norm; relu;
// bf16 store.

template<int CIN, int COUT, bool LAST>
__global__ __launch_bounds__(128,6) void k_sage(
    const void* __restrict__ hin, const int* __restrict__ off,
    const uint2* __restrict__ csr,
    const short* __restrict__ Wb, const void* __restrict__ bias,
    const int* __restrict__ flags, bf16* __restrict__ hout, void* __restrict__ outp)
{
  constexpr int RB   = CIN*2;                // bf16 row bytes: 128 or 160
  constexpr int KHT  = (CIN+31)/32;          // K-tiles per half: 2 or 3
  constexpr int KT   = 2*KHT;                // 4 or 6
  constexpr int NT   = (COUT+15)/16;         // 4 or 2
  constexpr int ROWB = KT*32*2;              // 256 or 384 bytes per A-row
  constexpr int LPE  = CIN/8;                // lanes per edge-row: 8 or 10
  constexpr int EPW  = 64/LPE;               // edges per wave load: 8 or 6

  __shared__ char smem[2*16*ROWB];

  const int f32m = flags[0];
  const int lane = threadIdx.x&63, wid = threadIdx.x>>6;
  const int wnode0 = blockIdx.x*32 + wid*16;
  char* lds = smem + wid*16*ROWB;

  const int sub = lane/LPE;
  const int cl  = lane - sub*LPE;
  const bool lact = (sub < EPW);
  const char* hinb = (const char*)hin;

  // ---- phase 1: gather + A-row staging ----
  for(int tt=0; tt<16; ++tt){
    const int node = wnode0 + tt;
    if(node >= N_NODES) continue;

    float a[8];
    #pragma unroll
    for(int k=0;k<8;k++) a[k]=0.f;

    const int e0 = off[node], e1 = off[node+1];
    for(int base=e0; base<e1; base+=64){
      const int cnt = min(64, e1-base);
      uint2 ev = (lane<cnt) ? csr[base+lane] : make_uint2(0u,0u);
      int   sv = (int)ev.x;
      float wv = LAST ? 1.f : __uint_as_float(ev.y);
      for(int j=0; j<cnt; j+=4*EPW){
        int ei0 = j+sub, ei1 = j+EPW+sub, ei2 = j+2*EPW+sub, ei3 = j+3*EPW+sub;
        bool v0 = lact && (ei0<cnt), v1 = lact && (ei1<cnt);
        bool v2 = lact && (ei2<cnt), v3 = lact && (ei3<cnt);
        int x0 = v0?ei0:0, x1 = v1?ei1:0, x2 = v2?ei2:0, x3 = v3?ei3:0;
        int   s0=__shfl(sv,x0), s1=__shfl(sv,x1), s2=__shfl(sv,x2), s3=__shfl(sv,x3);
        float w0=__shfl(wv,x0)*(v0?1.f:0.f), w1=__shfl(wv,x1)*(v1?1.f:0.f);
        float w2=__shfl(wv,x2)*(v2?1.f:0.f), w3=__shfl(wv,x3)*(v3?1.f:0.f);
        uint4 r0 = *(const uint4*)(hinb + (long)s0*RB + 16*cl);
        uint4 r1 = *(const uint4*)(hinb + (long)s1*RB + 16*cl);
        uint4 r2 = *(const uint4*)(hinb + (long)s2*RB + 16*cl);
        uint4 r3 = *(const uint4*)(hinb + (long)s3*RB + 16*cl);
        #define ACC8(rr,ww) \
          a[0]=fmaf(ww,__uint_as_float(rr.x<<16),a[0]); \
          a[1]=fmaf(ww,__uint_as_float(rr.x&0xffff0000u),a[1]); \
          a[2]=fmaf(ww,__uint_as_float(rr.y<<16),a[2]); \
          a[3]=fmaf(ww,__uint_as_float(rr.y&0xffff0000u),a[3]); \
          a[4]=fmaf(ww,__uint_as_float(rr.z<<16),a[4]); \
          a[5]=fmaf(ww,__uint_as_float(rr.z&0xffff0000u),a[5]); \
          a[6]=fmaf(ww,__uint_as_float(rr.w<<16),a[6]); \
          a[7]=fmaf(ww,__uint_as_float(rr.w&0xffff0000u),a[7]);
        ACC8(r0,w0); ACC8(r1,w1); ACC8(r2,w2); ACC8(r3,w3);
        #undef ACC8
      }
    }

    // reduce across edge groups -> lane q<LPE holds channels 8q..8q+7
    if(LPE==8){
      #pragma unroll
      for(int k=0;k<8;k++){
        a[k]+=__shfl_xor(a[k],8); a[k]+=__shfl_xor(a[k],16); a[k]+=__shfl_xor(a[k],32);
      }
    } else {
      #pragma unroll
      for(int k=0;k<8;k++){
        a[k] = __shfl(a[k],cl)    + __shfl(a[k],cl+10) + __shfl(a[k],cl+20)
             + __shfl(a[k],cl+30) + __shfl(a[k],cl+40) + __shfl(a[k],cl+50);
      }
    }
    const float inv = 1.f/fmaxf((float)(e1-e0), 1.f);

    const int sx = (tt&7)<<4;                       // row XOR swizzle
    if(lane < LPE){                                 // agg: 16B per lane
      u32 p0 = f2bf_rne(a[0]*inv) | (f2bf_rne(a[1]*inv)<<16);
      u32 p1 = f2bf_rne(a[2]*inv) | (f2bf_rne(a[3]*inv)<<16);
      u32 p2 = f2bf_rne(a[4]*inv) | (f2bf_rne(a[5]*inv)<<16);
      u32 p3 = f2bf_rne(a[6]*inv) | (f2bf_rne(a[7]*inv)<<16);
      int ob = tt*ROWB + lane*16;
      *(uint4*)(lds + (ob^sx)) = make_uint4(p0,p1,p2,p3);
    }
    if(CIN==80 && lane>=10 && lane<12){             // agg K-pad bytes 160..191
      int ob = tt*ROWB + lane*16;
      *(uint4*)(lds + (ob^sx)) = make_uint4(0u,0u,0u,0u);
    }
    const char* hsb = hinb + (long)__builtin_amdgcn_readfirstlane(node)*RB;
    if(lane < RB/16){                               // raw self-row copy
      uint4 hv = *(const uint4*)(hsb + lane*16);
      int ob = tt*ROWB + KHT*64 + lane*16;
      *(uint4*)(lds + (ob^sx)) = hv;
    }
    if(CIN==80 && lane>=20 && lane<22){             // h K-pad bytes 352..383
      int ob = tt*ROWB + KHT*64 + (lane-10)*16;
      *(uint4*)(lds + (ob^sx)) = make_uint4(0u,0u,0u,0u);
    }
  }

  // ---- phase 2: MFMA matvec (wave-local LDS reads) ----
  f32x4 acc[NT];
  #pragma unroll
  for(int nt=0; nt<NT; ++nt){
    int col = nt*16 + (lane&15);
    float bv = (col<COUT) ? ldf(bias,col,f32m) : 0.f;
    acc[nt] = (f32x4){bv,bv,bv,bv};
  }
  const int arow = lane&15, kgrp = lane>>4;
  #pragma unroll
  for(int kt=0; kt<KT; ++kt){
    int ob = arow*ROWB + kt*64 + kgrp*16;
    short8 a8 = *(const short8*)(lds + (ob ^ ((arow&7)<<4)));
    #pragma unroll
    for(int nt=0; nt<NT; ++nt){
      short8 b8 = *(const short8*)(Wb + ((long)(kt*NT+nt)*64 + lane)*8);
      acc[nt] = __builtin_amdgcn_mfma_f32_16x16x32_bf16(a8, b8, acc[nt], 0,0,0);
    }
  }

  // ---- epilogue: L2-norm per row, relu, store ----
  float sq[4];
  #pragma unroll
  for(int r=0;r<4;r++){
    float s = 0.f;
    #pragma unroll
    for(int nt=0;nt<NT;nt++){ float v = acc[nt][r]; s = fmaf(v,v,s); }
    #pragma unroll
    for(int d=1; d<16; d<<=1) s += __shfl_xor(s, d);
    sq[r] = s;
  }
  #pragma unroll
  for(int r=0;r<4;r++){
    float rn = 1.f/fmaxf(sqrtf(sq[r]), 1e-12f);
    const int node = wnode0 + 4*(lane>>4) + r;
    #pragma unroll
    for(int nt=0;nt<NT;nt++){
      int col = nt*16 + (lane&15);
      float v = acc[nt][r]*rn;
      if(!LAST) v = fmaxf(v,0.f);
      if(node < N_NODES && col < COUT){
        if(LAST){
          long oi = (long)node*COUT + col;
          if(f32m) ((float*)outp)[oi] = v;
          else     ((bf16*)outp)[oi]  = __float2bfloat16(v);
        } else {
          hout[(long)node*64 + col] = __float2bfloat16(v);
        }
      }
    }
  }
}

// ---------------- launch ----------------

extern "C" void kernel_launch(void* const* d_in, const int* in_sizes, int n_in,
                              void* d_out, int out_size, void* d_ws, size_t ws_size,
                              hipStream_t stream){
  const void* x    = d_in[0];
  const int*  ei   = (const int*)d_in[1];
  const void* ew   = d_in[2];
  const void* embW = d_in[3];
  const void* embB = d_in[4];
  const void *Wl0=d_in[5],  *Wr0=d_in[6],  *b0=d_in[7];
  const void *Wl1=d_in[8],  *Wr1=d_in[9],  *b1=d_in[10];
  const void *Wl2=d_in[11], *Wr2=d_in[12], *b2=d_in[13];
  const void *Wl3=d_in[14], *Wr3=d_in[15], *b3=d_in[16];
  const void *Wlo=d_in[17], *Wro=d_in[18], *bo=d_in[19];

  // 256B-aligned workspace carves (uint4/short8 targets must be 16B-aligned)
  char* w = (char*)d_ws;
  auto carve = [&](size_t nbytes)->char*{
    char* r = w; w += (nbytes + 255) & ~(size_t)255; return r;
  };
  int*   flags   = (int*)carve(16);
  int*   deg     = (int*)carve((size_t)N_NODES*4);
  int*   cur     = (int*)carve((size_t)N_NODES*4);
  int*   off     = (int*)carve((size_t)(N_NODES+1)*4);
  int*   bsum    = (int*)carve((size_t)SCAN_BLOCKS*4);
  int*   bbase   = (int*)carve((size_t)SCAN_BLOCKS*4);
  uint2* csr     = (uint2*)carve((size_t)N_EDGES*8);
  short* Wb0     = (short*)carve((size_t)6*4*512*2);
  short* Wb1     = (short*)carve((size_t)4*4*512*2);
  short* Wb2     = (short*)carve((size_t)4*4*512*2);
  short* Wb3     = (short*)carve((size_t)4*4*512*2);
  short* Wbo     = (short*)carve((size_t)4*2*512*2);
  float* Wef     = (float*)carve((size_t)8000*4);
  float* bef     = (float*)carve((size_t)80*4);
  bf16*  hE      = (bf16*)carve((size_t)N_NODES*80*2);   // embed out, 160B rows
  bf16*  hA      = (bf16*)carve((size_t)N_NODES*64*2);   // 128B rows
  bf16*  hB      = (bf16*)carve((size_t)N_NODES*64*2);

  k_detect<<<1, 256, 0, stream>>>((const u32*)x, ei, flags);
  k_zero2<<<(N_NODES+255)/256, 256, 0, stream>>>(deg, cur);
  k_count<<<N_EDGES/256, 256, 0, stream>>>(ei, flags, deg);
  k_scan1<<<SCAN_BLOCKS, 256, 0, stream>>>(deg, off, bsum);
  k_scan2<<<1, 512, 0, stream>>>(bsum, bbase);
  k_scan3<<<SCAN_BLOCKS, 256, 0, stream>>>(off, bbase);
  k_fill <<<8*(N_EDGES/256), 256, 0, stream>>>(ei, ew, flags, off, cur, csr);

  k_cvt  <<<32, 256, 0, stream>>>(embW, embB, flags, Wef, bef);
  k_packb<<<48, 256, 0, stream>>>(Wl0, Wr0, flags, 80, 64, 6, 4, Wb0);
  k_packb<<<32, 256, 0, stream>>>(Wl1, Wr1, flags, 64, 64, 4, 4, Wb1);
  k_packb<<<32, 256, 0, stream>>>(Wl2, Wr2, flags, 64, 64, 4, 4, Wb2);
  k_packb<<<32, 256, 0, stream>>>(Wl3, Wr3, flags, 64, 64, 4, 4, Wb3);
  k_packb<<<16, 256, 0, stream>>>(Wlo, Wro, flags, 64, 18, 4, 2, Wbo);

  k_embed<<<(N_NODES+63)/64, 256, 0, stream>>>(x, Wef, bef, flags, hE);

  const int NBLK = (N_NODES+31)/32;   // 3125 exact
  k_sage<80,64,false><<<NBLK, 128, 0, stream>>>(hE, off, csr, Wb0, b0, flags, hA, nullptr);
  k_sage<64,64,false><<<NBLK, 128, 0, stream>>>(hA, off, csr, Wb1, b1, flags, hB, nullptr);
  k_sage<64,64,false><<<NBLK, 128, 0, stream>>>(hB, off, csr, Wb2, b2, flags, hA, nullptr);
  k_sage<64,64,false><<<NBLK, 128, 0, stream>>>(hA, off, csr, Wb3, b3, flags, hB, nullptr);
  k_sage<64,18,true ><<<NBLK, 128, 0, stream>>>(hB, off, csr, Wbo, bo, flags, nullptr, d_out);
}